// Round 1
// baseline (7446.317 us; speedup 1.0000x reference)
//
#include <hip/hip_runtime.h>
#include <math.h>

#define NE 1024      // embed dim
#define NT 12        // frames / seq len
#define NCPT 4       // channels per timestep
#define ND 64        // d_model
#define NHD 16       // head dim
#define NFF 256      // ff dim
#define NEPS 1e-5f

#define LDSTRIDE 65              // padded row stride for attention buffers
#define ABUF (NT*LDSTRIDE)       // 780 floats per buffer
#define WAVEBUF (4*ABUF)         // q,k,v,o per wave = 3120 floats
#define SMEM2_FLOATS (8*WAVEBUF) // 24960 >= 12288 (xs slice)

__global__ __launch_bounds__(512, 2) void prithvi_fused(
    const float* __restrict__ x,     const float* __restrict__ conv_w,
    const float* __restrict__ bn_g,  const float* __restrict__ bn_b,
    const float* __restrict__ bn_m,  const float* __restrict__ bn_v,
    const float* __restrict__ w_in,  const float* __restrict__ qkv_w,
    const float* __restrict__ qkv_b, const float* __restrict__ ow,
    const float* __restrict__ ob,    const float* __restrict__ ln1_g,
    const float* __restrict__ ln1_b, const float* __restrict__ ff1_w,
    const float* __restrict__ ff1_b, const float* __restrict__ ff2_w,
    const float* __restrict__ ff2_b, const float* __restrict__ ln2_g,
    const float* __restrict__ ln2_b, const float* __restrict__ w_out,
    const float* __restrict__ b_out, float* __restrict__ out)
{
  __shared__ float g[NE*NT];          // conv+bn+gelu output, [o][t], 48KB
  __shared__ float smem2[SMEM2_FLOATS]; // phase1-2: xs slice; phase3: per-wave attn buffers

  const int sp   = blockIdx.x;        // hp*16 + wp
  const int tid  = threadIdx.x;
  const int lane = tid & 63;
  const int wave = tid >> 6;

  // ---------- phase 1: stage x slice: xs[e*NT + t] = x[(e*NT+t)*256 + sp] ----------
  float* xs = smem2;
  for (int ch = tid; ch < NE*NT; ch += 512)
    xs[ch] = x[(size_t)ch*256 + sp];
  __syncthreads();

  // ---------- phase 2: 1x1 conv + BN(eval) + exact GELU -> g[o*NT+t] ----------
  {
    float acc[2][NT];
    #pragma unroll
    for (int j=0;j<2;++j)
      #pragma unroll
      for (int t=0;t<NT;++t) acc[j][t]=0.f;
    const float* w0p = conv_w + (size_t)tid*NE;
    const float* w1p = conv_w + (size_t)(tid+512)*NE;
    for (int e=0;e<NE;e+=4) {
      float4 wa = *(const float4*)(w0p+e);
      float4 wb = *(const float4*)(w1p+e);
      #pragma unroll
      for (int ee=0;ee<4;++ee) {
        const float* xr = xs + (e+ee)*NT;   // broadcast across wave
        float wA = (&wa.x)[ee];
        float wB = (&wb.x)[ee];
        #pragma unroll
        for (int t=0;t<NT;++t) {
          float xv = xr[t];
          acc[0][t] = fmaf(xv, wA, acc[0][t]);
          acc[1][t] = fmaf(xv, wB, acc[1][t]);
        }
      }
    }
    #pragma unroll
    for (int j=0;j<2;++j) {
      int o = tid + j*512;
      float sc = bn_g[o] * rsqrtf(bn_v[o] + NEPS);
      float sh = bn_b[o] - bn_m[o]*sc;
      #pragma unroll
      for (int t=0;t<NT;++t) {
        float z  = fmaf(acc[j][t], sc, sh);
        float ge = 0.5f*z*(1.f + erff(z*0.70710678118654752f));
        g[o*NT+t] = ge;
      }
    }
  }
  __syncthreads();
  // g is read-only from here on.

  // ---------- per-lane constants ----------
  const float wi0 = w_in[lane*4+0], wi1 = w_in[lane*4+1],
              wi2 = w_in[lane*4+2], wi3 = w_in[lane*4+3];
  float pe[NT];
  {
    // div_i = exp(-2i*ln(1e4)/64); lane d -> i = d/2; even: sin, odd: cos
    float freq = expf(-(float)(lane & ~1) * (9.210340371976184f/64.f));
    #pragma unroll
    for (int t=0;t<NT;++t) {
      float a = freq * (float)t;
      pe[t] = (lane & 1) ? cosf(a) : sinf(a);
    }
  }
  const float wout_lane = w_out[lane];

  float* aq = smem2 + wave*WAVEBUF;
  float* ak = aq + ABUF;
  float* av = ak + ABUF;
  float* ao = av + ABUF;

  // ---------- phase 3: one sequence per wave, 32 iterations ----------
  for (int it=0; it<32; ++it) {
    const int s = it*8 + wave;   // sub-pixel (r1,r2) = (s>>4, s&15)

    // h0 = shuffled-gelu @ w_in.T + pos_encoding   (lane owns column d = lane)
    float h[NT];
    #pragma unroll
    for (int t=0;t<NT;++t) {
      float v0 = g[(0*256+s)*NT+t];
      float v1 = g[(1*256+s)*NT+t];
      float v2 = g[(2*256+s)*NT+t];
      float v3 = g[(3*256+s)*NT+t];
      h[t] = fmaf(v0,wi0, fmaf(v1,wi1, fmaf(v2,wi2, fmaf(v3,wi3, pe[t]))));
    }

    for (int l=0;l<2;++l) {
      // ---- qkv: lane computes q/k/v column `lane` ----
      const float* Wq = qkv_w + ((size_t)l*192 + lane)*64;
      const float* Wk = Wq + 64*64;
      const float* Wv = Wq + 128*64;
      const float* bq = qkv_b + l*192;
      float q[NT], k[NT], v[NT];
      {
        float b0 = bq[lane], b1 = bq[64+lane], b2 = bq[128+lane];
        #pragma unroll
        for (int t=0;t<NT;++t) { q[t]=b0; k[t]=b1; v[t]=b2; }
      }
      for (int d=0; d<64; d+=4) {
        float4 wq4 = *(const float4*)(Wq+d);
        float4 wk4 = *(const float4*)(Wk+d);
        float4 wv4 = *(const float4*)(Wv+d);
        #pragma unroll
        for (int dd=0;dd<4;++dd) {
          float w0=(&wq4.x)[dd], w1=(&wk4.x)[dd], w2=(&wv4.x)[dd];
          #pragma unroll
          for (int t=0;t<NT;++t) {
            float hv = __shfl(h[t], d+dd);
            q[t]=fmaf(hv,w0,q[t]); k[t]=fmaf(hv,w1,k[t]); v[t]=fmaf(hv,w2,v[t]);
          }
        }
      }
      // stage q,k,v in per-wave LDS
      #pragma unroll
      for (int t=0;t<NT;++t) {
        aq[t*LDSTRIDE+lane]=q[t];
        ak[t*LDSTRIDE+lane]=k[t];
        av[t*LDSTRIDE+lane]=v[t];
      }
      asm volatile("s_waitcnt lgkmcnt(0)" ::: "memory");

      // ---- attention: lane = (head hh, query row tq), lanes 0..47 ----
      if (lane < 48) {
        const int hh = lane / 12;
        const int tq = lane % 12;
        float sc[NT];
        #pragma unroll
        for (int tk=0;tk<NT;++tk) {
          float ssum=0.f;
          #pragma unroll
          for (int e2=0;e2<NHD;++e2)
            ssum = fmaf(aq[tq*LDSTRIDE+hh*16+e2], ak[tk*LDSTRIDE+hh*16+e2], ssum);
          sc[tk] = ssum * 0.25f;   // 1/sqrt(16)
        }
        float mx = sc[0];
        #pragma unroll
        for (int tk=1;tk<NT;++tk) mx = fmaxf(mx, sc[tk]);
        float ssum=0.f;
        #pragma unroll
        for (int tk=0;tk<NT;++tk) { sc[tk] = expf(sc[tk]-mx); ssum += sc[tk]; }
        float inv = 1.f/ssum;
        float oa[NHD];
        #pragma unroll
        for (int e2=0;e2<NHD;++e2) oa[e2]=0.f;
        #pragma unroll
        for (int tk=0;tk<NT;++tk) {
          float a = sc[tk]*inv;
          #pragma unroll
          for (int e2=0;e2<NHD;++e2)
            oa[e2] = fmaf(a, av[tk*LDSTRIDE+hh*16+e2], oa[e2]);
        }
        #pragma unroll
        for (int e2=0;e2<NHD;++e2) ao[tq*LDSTRIDE+hh*16+e2] = oa[e2];
      }
      asm volatile("s_waitcnt lgkmcnt(0)" ::: "memory");

      // ---- o-proj + bias + residual ----
      {
        const float* Wor = ow + ((size_t)l*64 + lane)*64;
        float obv = ob[l*64+lane];
        float pr[NT];
        #pragma unroll
        for (int t=0;t<NT;++t) pr[t]=obv;
        for (int j=0;j<64;j+=4) {
          float4 w4 = *(const float4*)(Wor+j);
          #pragma unroll
          for (int jj=0;jj<4;++jj) {
            float w=(&w4.x)[jj];
            #pragma unroll
            for (int t=0;t<NT;++t)
              pr[t] = fmaf(ao[t*LDSTRIDE+j+jj], w, pr[t]);  // broadcast read
          }
        }
        #pragma unroll
        for (int t=0;t<NT;++t) h[t] += pr[t];
      }
      // ---- LN1 (over d = lanes) ----
      {
        float g1 = ln1_g[l*64+lane], b1 = ln1_b[l*64+lane];
        #pragma unroll
        for (int t=0;t<NT;++t) {
          float xv = h[t];
          float sm = xv;
          #pragma unroll
          for (int off=1; off<64; off<<=1) sm += __shfl_xor(sm, off);
          float mean = sm * (1.f/64.f);
          float dlt = xv - mean;
          float vs = dlt*dlt;
          #pragma unroll
          for (int off=1; off<64; off<<=1) vs += __shfl_xor(vs, off);
          float var = vs * (1.f/64.f);
          h[t] = fmaf(dlt * rsqrtf(var + NEPS), g1, b1);
        }
      }
      // ---- FF: f = relu(h@W1.T+b1)@W2.T+b2 ; lane owns ff cols lane+64j ----
      {
        const float* W1 = ff1_w + (size_t)l*NFF*ND;
        float f[4][NT];
        #pragma unroll
        for (int j=0;j<4;++j) {
          float bb = ff1_b[l*NFF + j*64 + lane];
          #pragma unroll
          for (int t=0;t<NT;++t) f[j][t]=bb;
        }
        for (int d=0; d<64; d+=4) {
          float4 w4[4];
          #pragma unroll
          for (int j=0;j<4;++j)
            w4[j] = *(const float4*)(W1 + (size_t)(j*64+lane)*64 + d);
          #pragma unroll
          for (int dd=0;dd<4;++dd) {
            #pragma unroll
            for (int t=0;t<NT;++t) {
              float hb = __shfl(h[t], d+dd);
              #pragma unroll
              for (int j=0;j<4;++j)
                f[j][t] = fmaf(hb, (&w4[j].x)[dd], f[j][t]);
            }
          }
        }
        #pragma unroll
        for (int j=0;j<4;++j)
          #pragma unroll
          for (int t=0;t<NT;++t) f[j][t] = fmaxf(f[j][t], 0.f);

        const float* W2r = ff2_w + ((size_t)l*64 + lane)*NFF;
        float pr2[NT];
        {
          float f2b = ff2_b[l*64+lane];
          #pragma unroll
          for (int t=0;t<NT;++t) pr2[t]=f2b;
        }
        #pragma unroll
        for (int j=0;j<4;++j) {
          for (int d=0; d<64; d+=4) {
            float4 w4 = *(const float4*)(W2r + j*64 + d);
            #pragma unroll
            for (int dd=0;dd<4;++dd) {
              float w=(&w4.x)[dd];
              #pragma unroll
              for (int t=0;t<NT;++t)
                pr2[t] = fmaf(__shfl(f[j][t], d+dd), w, pr2[t]);
            }
          }
        }
        #pragma unroll
        for (int t=0;t<NT;++t) h[t] += pr2[t];
      }
      // ---- LN2 ----
      {
        float g2 = ln2_g[l*64+lane], b2 = ln2_b[l*64+lane];
        #pragma unroll
        for (int t=0;t<NT;++t) {
          float xv = h[t];
          float sm = xv;
          #pragma unroll
          for (int off=1; off<64; off<<=1) sm += __shfl_xor(sm, off);
          float mean = sm * (1.f/64.f);
          float dlt = xv - mean;
          float vs = dlt*dlt;
          #pragma unroll
          for (int off=1; off<64; off<<=1) vs += __shfl_xor(vs, off);
          float var = vs * (1.f/64.f);
          h[t] = fmaf(dlt * rsqrtf(var + NEPS), g2, b2);
        }
      }
    } // layer loop

    // ---- head: mean over T, @ w_out.T, sigmoid ----
    {
      float m = 0.f;
      #pragma unroll
      for (int t=0;t<NT;++t) m += h[t];
      m *= (1.f/12.f);
      float c = m * wout_lane;
      #pragma unroll
      for (int off=1; off<64; off<<=1) c += __shfl_xor(c, off);
      if (lane == 0) {
        float logit = c + b_out[0];
        int r1 = s >> 4, r2 = s & 15;
        int hf = (sp >> 4)*16 + r1;
        int wf = (sp & 15)*16 + r2;
        out[hf*256 + wf] = 1.f/(1.f + expf(-logit));
      }
    }
  } // it loop
}

extern "C" void kernel_launch(void* const* d_in, const int* in_sizes, int n_in,
                              void* d_out, int out_size, void* d_ws, size_t ws_size,
                              hipStream_t stream) {
  (void)in_sizes; (void)n_in; (void)d_ws; (void)ws_size; (void)out_size;
  prithvi_fused<<<256, 512, 0, stream>>>(
    (const float*)d_in[0],  (const float*)d_in[1],  (const float*)d_in[2],
    (const float*)d_in[3],  (const float*)d_in[4],  (const float*)d_in[5],
    (const float*)d_in[6],  (const float*)d_in[7],  (const float*)d_in[8],
    (const float*)d_in[9],  (const float*)d_in[10], (const float*)d_in[11],
    (const float*)d_in[12], (const float*)d_in[13], (const float*)d_in[14],
    (const float*)d_in[15], (const float*)d_in[16], (const float*)d_in[17],
    (const float*)d_in[18], (const float*)d_in[19], (const float*)d_in[20],
    (float*)d_out);
}

// Round 2
// 6658.203 us; speedup vs baseline: 1.1184x; 1.1184x over previous
//
#include <hip/hip_runtime.h>
#include <math.h>

// ---------------- constants ----------------
// E=1024, T=12, CPT=4, D=64, NH=4, HD=16, FF=256, L=2
// 256 spatial cells (blocks); per cell 256 sequences of (T=12, D=64).
// Phase 3: lane = (sl, t): sl = sub-sequence slot 0..4 (5 seqs/wave), t = 0..11.
// 8 waves x 5 seqs = 40 seqs per pass, 7 passes cover 256.

#define LGKM0 asm volatile("s_waitcnt lgkmcnt(0)" ::: "memory")

// 4-output-row matmul quad: A0..A3 = bias[R..R+3] + W[R..R+3][:] . SRC[0:64]
#define QUAD_MM(WROW, BPTR, R, A0, A1, A2, A3, SRC)                         \
  {                                                                         \
    const float* _w = (WROW);                                               \
    A0 = (BPTR)[(R)];                                                       \
    A1 = (BPTR)[(R) + 1];                                                   \
    A2 = (BPTR)[(R) + 2];                                                   \
    A3 = (BPTR)[(R) + 3];                                                   \
    _Pragma("unroll") for (int _d = 0; _d < 64; ++_d) {                     \
      float _hv = SRC[_d];                                                  \
      A0 = fmaf(_w[_d], _hv, A0);                                           \
      A1 = fmaf(_w[64 + _d], _hv, A1);                                      \
      A2 = fmaf(_w[128 + _d], _hv, A2);                                     \
      A3 = fmaf(_w[192 + _d], _hv, A3);                                     \
    }                                                                       \
  }

#define LAYERNORM(GP, BP)                                                   \
  {                                                                         \
    float s1[32];                                                           \
    _Pragma("unroll") for (int i = 0; i < 32; ++i)                          \
        s1[i] = h[2 * i] + h[2 * i + 1];                                    \
    _Pragma("unroll") for (int i = 0; i < 16; ++i) s1[i] += s1[i + 16];     \
    _Pragma("unroll") for (int i = 0; i < 8; ++i) s1[i] += s1[i + 8];       \
    _Pragma("unroll") for (int i = 0; i < 4; ++i) s1[i] += s1[i + 4];       \
    float m_ = (s1[0] + s1[1] + s1[2] + s1[3]) * (1.f / 64.f);              \
    float q1[32];                                                           \
    _Pragma("unroll") for (int i = 0; i < 32; ++i) {                        \
      float d0_ = h[2 * i] - m_, d1_ = h[2 * i + 1] - m_;                   \
      q1[i] = fmaf(d0_, d0_, d1_ * d1_);                                    \
    }                                                                       \
    _Pragma("unroll") for (int i = 0; i < 16; ++i) q1[i] += q1[i + 16];     \
    _Pragma("unroll") for (int i = 0; i < 8; ++i) q1[i] += q1[i + 8];       \
    _Pragma("unroll") for (int i = 0; i < 4; ++i) q1[i] += q1[i + 4];       \
    float v_ = (q1[0] + q1[1] + q1[2] + q1[3]) * (1.f / 64.f);              \
    float rs_ = rsqrtf(v_ + 1e-5f);                                         \
    _Pragma("unroll") for (int d = 0; d < 64; ++d)                          \
        h[d] = fmaf((h[d] - m_) * rs_, (GP)[d], (BP)[d]);                   \
  }

__global__ __launch_bounds__(512, 2) void prithvi_fused(
    const float* __restrict__ x,     const float* __restrict__ conv_w,
    const float* __restrict__ bn_g,  const float* __restrict__ bn_b,
    const float* __restrict__ bn_m,  const float* __restrict__ bn_v,
    const float* __restrict__ w_in,  const float* __restrict__ qkv_w,
    const float* __restrict__ qkv_b, const float* __restrict__ ow,
    const float* __restrict__ ob,    const float* __restrict__ ln1_g,
    const float* __restrict__ ln1_b, const float* __restrict__ ff1_w,
    const float* __restrict__ ff1_b, const float* __restrict__ ff2_w,
    const float* __restrict__ ff2_b, const float* __restrict__ ln2_g,
    const float* __restrict__ ln2_b, const float* __restrict__ w_out,
    const float* __restrict__ b_out, float* __restrict__ out)
{
  // sbuf: phase1 = x-slice transposed [t][e] (12x1024); phase2 output g [o][t] (1024x12)
  __shared__ __align__(16) float sbuf[12288];              // 48 KB
  // per-wave row buffer: 64 rows x 36 words (rows: row = t*5+sl)
  __shared__ __align__(16) float Tbuf[8 * 64 * 36];        // 72 KB

  const int sp   = blockIdx.x;    // hp*16 + wp
  const int tid  = threadIdx.x;
  const int lane = tid & 63;
  const int wave = tid >> 6;

  // ---------------- phase 1: stage x slice transposed: sbuf[t*1024+e] ----------------
  for (int ch = tid; ch < 12288; ch += 512) {
    int e = ch / 12;
    int t = ch - e * 12;
    sbuf[t * 1024 + e] = x[(size_t)ch * 256 + sp];
  }
  __syncthreads();

  // ---------------- phase 2: 1x1 conv (acc in regs) ----------------
  float acc0[12], acc1[12];
#pragma unroll
  for (int t = 0; t < 12; ++t) { acc0[t] = 0.f; acc1[t] = 0.f; }
  {
    const float* w0p = conv_w + tid * 1024;
    const float* w1p = conv_w + (tid + 512) * 1024;
    for (int eb = 0; eb < 1024; eb += 4) {
      float4 wa = *(const float4*)(w0p + eb);
      float4 wb = *(const float4*)(w1p + eb);
#pragma unroll
      for (int t = 0; t < 12; ++t) {
        float4 xv = *(const float4*)&sbuf[t * 1024 + eb];
        acc0[t] = fmaf(xv.x, wa.x, acc0[t]);
        acc0[t] = fmaf(xv.y, wa.y, acc0[t]);
        acc0[t] = fmaf(xv.z, wa.z, acc0[t]);
        acc0[t] = fmaf(xv.w, wa.w, acc0[t]);
        acc1[t] = fmaf(xv.x, wb.x, acc1[t]);
        acc1[t] = fmaf(xv.y, wb.y, acc1[t]);
        acc1[t] = fmaf(xv.z, wb.z, acc1[t]);
        acc1[t] = fmaf(xv.w, wb.w, acc1[t]);
      }
    }
  }
  __syncthreads();   // all xs reads done; sbuf now becomes g
  {
    int o0 = tid;
    float sc0 = bn_g[o0] * rsqrtf(bn_v[o0] + 1e-5f);
    float sh0 = fmaf(-bn_m[o0], sc0, bn_b[o0]);
#pragma unroll
    for (int t = 0; t < 12; ++t) {
      float z = fmaf(acc0[t], sc0, sh0);
      sbuf[o0 * 12 + t] = 0.5f * z * (1.f + erff(z * 0.70710678118654752f));
    }
    int o1 = tid + 512;
    float sc1 = bn_g[o1] * rsqrtf(bn_v[o1] + 1e-5f);
    float sh1 = fmaf(-bn_m[o1], sc1, bn_b[o1]);
#pragma unroll
    for (int t = 0; t < 12; ++t) {
      float z = fmaf(acc1[t], sc1, sh1);
      sbuf[o1 * 12 + t] = 0.5f * z * (1.f + erff(z * 0.70710678118654752f));
    }
  }
  __syncthreads();
  // sbuf (= g[o*12+t]) read-only from here.

  // ---------------- phase 3: lane = (sl, t) ----------------
  const int sl  = lane / 12;                 // 0..5 (5 = idle slot)
  const int t   = lane - sl * 12;            // 0..11 (0..3 for sl==5)
  const int slc = (sl < 5) ? sl : 4;         // clamped for reads
  const int rowi = (sl < 5) ? (t * 5 + sl) : (60 + t);
  float* Tw   = Tbuf + wave * (64 * 36);
  float* rowW = Tw + rowi * 36;
  const float tf = (float)t;

#pragma unroll 1
  for (int it = 0; it < 7; ++it) {
    const int s_raw = it * 40 + wave * 5 + sl;
    const bool valid = (sl < 5) && (s_raw < 256);
    const int s = valid ? s_raw : 0;

    // ---- h0 = g4 @ w_in.T + pos_encoding ----
    float h[64];
    {
      const int gb = s * 12 + t;
      const float g0 = sbuf[gb];
      const float g1 = sbuf[3072 + gb];
      const float g2 = sbuf[6144 + gb];
      const float g3 = sbuf[9216 + gb];
      float freq = 1.f;                       // exp(-2i*ln(1e4)/64)^i, i=0..31
#pragma unroll
      for (int i = 0; i < 32; ++i) {
        float ang = tf * freq;
        float sv = sinf(ang), cv = cosf(ang);
        const float* wi = w_in + 8 * i;
        h[2 * i]     = fmaf(g0, wi[0], fmaf(g1, wi[1], fmaf(g2, wi[2], fmaf(g3, wi[3], sv))));
        h[2 * i + 1] = fmaf(g0, wi[4], fmaf(g1, wi[5], fmaf(g2, wi[6], fmaf(g3, wi[7], cv))));
        freq *= 0.74989420933245580f;         // exp(-2*ln(1e4)/64)
      }
    }

#pragma unroll 1
    for (int l = 0; l < 2; ++l) {
      const float* Wb = qkv_w + l * 192 * 64;
      const float* Bb = qkv_b + l * 192;
      float att[2][12];
      float o[64];
#pragma unroll
      for (int d = 0; d < 64; ++d) o[d] = 0.f;

#pragma unroll
      for (int half = 0; half < 2; ++half) {
        // ---- K chunk (k dims half*32 .. +31) -> LDS words 0..31 ----
        LGKM0;
#pragma unroll 1
        for (int dp = 0; dp < 32; dp += 4) {
          int r = 64 + half * 32 + dp;
          float a0, a1, a2, a3;
          QUAD_MM(Wb + r * 64, Bb, r, a0, a1, a2, a3, h);
          *(float4*)(rowW + dp) = make_float4(a0, a1, a2, a3);
        }
        LGKM0;
        // ---- Q (heads 2*half, 2*half+1) fused with scores ----
#pragma unroll
        for (int hp = 0; hp < 2; ++hp) {
#pragma unroll
          for (int tk = 0; tk < 12; ++tk) att[hp][tk] = 0.f;
#pragma unroll 1
          for (int qq = 0; qq < 4; ++qq) {
            int r = half * 32 + hp * 16 + qq * 4;   // q row
            float a0, a1, a2, a3;
            QUAD_MM(Wb + r * 64, Bb, r, a0, a1, a2, a3, h);
            int w = hp * 16 + qq * 4;               // k word in row
#pragma unroll
            for (int tk = 0; tk < 12; ++tk) {
              const float4 kv = *(const float4*)(Tw + (tk * 5 + slc) * 36 + w);
              att[hp][tk] = fmaf(a0, kv.x, fmaf(a1, kv.y, fmaf(a2, kv.z, fmaf(a3, kv.w, att[hp][tk]))));
            }
          }
          // softmax (lane-local), scale 1/sqrt(16)=0.25 folded in
          float mx = att[hp][0];
#pragma unroll
          for (int tk = 1; tk < 12; ++tk) mx = fmaxf(mx, att[hp][tk]);
          float sum = 0.f;
#pragma unroll
          for (int tk = 0; tk < 12; ++tk) {
            float e = expf((att[hp][tk] - mx) * 0.25f);
            att[hp][tk] = e;
            sum += e;
          }
          float inv = 1.f / sum;
#pragma unroll
          for (int tk = 0; tk < 12; ++tk) att[hp][tk] *= inv;
        }
        // ---- V chunk (v dims half*32 .. +31) ----
        LGKM0;
#pragma unroll 1
        for (int dp = 0; dp < 32; dp += 4) {
          int r = 128 + half * 32 + dp;
          float a0, a1, a2, a3;
          QUAD_MM(Wb + r * 64, Bb, r, a0, a1, a2, a3, h);
          *(float4*)(rowW + dp) = make_float4(a0, a1, a2, a3);
        }
        LGKM0;
        // ---- PV: o[half*32 .. +31] ----
#pragma unroll
        for (int tk = 0; tk < 12; ++tk) {
          const float* vr = Tw + (tk * 5 + slc) * 36;
          float a0 = att[0][tk], a1 = att[1][tk];
#pragma unroll
          for (int dq = 0; dq < 8; ++dq) {
            float4 vv = *(const float4*)(vr + dq * 4);
            float aa = (dq < 4) ? a0 : a1;
            int ob_ = half * 32 + dq * 4;
            o[ob_ + 0] = fmaf(aa, vv.x, o[ob_ + 0]);
            o[ob_ + 1] = fmaf(aa, vv.y, o[ob_ + 1]);
            o[ob_ + 2] = fmaf(aa, vv.z, o[ob_ + 2]);
            o[ob_ + 3] = fmaf(aa, vv.w, o[ob_ + 3]);
          }
        }
      } // half

      // ---- o-proj + residual (two halves through LDS row) ----
      {
        const float* WO  = ow + l * 64 * 64;
        const float* BOp = ob + l * 64;
#pragma unroll
        for (int half = 0; half < 2; ++half) {
          LGKM0;
#pragma unroll 1
          for (int dp = 0; dp < 32; dp += 4) {
            int r = half * 32 + dp;
            float a0, a1, a2, a3;
            QUAD_MM(WO + r * 64, BOp, r, a0, a1, a2, a3, o);
            *(float4*)(rowW + dp) = make_float4(a0, a1, a2, a3);
          }
          LGKM0;
#pragma unroll
          for (int dq = 0; dq < 8; ++dq) {
            float4 r4 = *(const float4*)(rowW + dq * 4);
            int hb = half * 32 + dq * 4;
            h[hb + 0] += r4.x;
            h[hb + 1] += r4.y;
            h[hb + 2] += r4.z;
            h[hb + 3] += r4.w;
          }
        }
      }
      // ---- LN1 ----
      LAYERNORM(ln1_g + l * 64, ln1_b + l * 64);

      // ---- FF: chunks of 32 ff-dims through LDS row ----
      {
        float facc[64];
#pragma unroll
        for (int d = 0; d < 64; ++d) facc[d] = ff2_b[l * 64 + d];
        const float* W1 = ff1_w + l * 256 * 64;
        const float* B1 = ff1_b + l * 256;
        const float* W2 = ff2_w + l * 64 * 256;
#pragma unroll 1
        for (int chk = 0; chk < 8; ++chk) {
          LGKM0;
#pragma unroll 1
          for (int fp = 0; fp < 32; fp += 4) {
            int r = chk * 32 + fp;
            float a0, a1, a2, a3;
            QUAD_MM(W1 + r * 64, B1, r, a0, a1, a2, a3, h);
            a0 = fmaxf(a0, 0.f);
            a1 = fmaxf(a1, 0.f);
            a2 = fmaxf(a2, 0.f);
            a3 = fmaxf(a3, 0.f);
            *(float4*)(rowW + fp) = make_float4(a0, a1, a2, a3);
          }
          LGKM0;
#pragma unroll 1
          for (int sub = 0; sub < 4; ++sub) {
            float4 xa = *(const float4*)(rowW + sub * 8);
            float4 xb = *(const float4*)(rowW + sub * 8 + 4);
            int cb = chk * 32 + sub * 8;
#pragma unroll
            for (int d2 = 0; d2 < 64; ++d2) {
              const float* w2r = W2 + d2 * 256 + cb;
              float t0 = fmaf(w2r[0], xa.x, facc[d2]);
              t0 = fmaf(w2r[1], xa.y, t0);
              t0 = fmaf(w2r[2], xa.z, t0);
              t0 = fmaf(w2r[3], xa.w, t0);
              t0 = fmaf(w2r[4], xb.x, t0);
              t0 = fmaf(w2r[5], xb.y, t0);
              t0 = fmaf(w2r[6], xb.z, t0);
              facc[d2] = fmaf(w2r[7], xb.w, t0);
            }
          }
        }
#pragma unroll
        for (int d = 0; d < 64; ++d) h[d] += facc[d];
      }
      // ---- LN2 ----
      LAYERNORM(ln2_g + l * 64, ln2_b + l * 64);
    } // layer

    // ---- head: mean over t, dot w_out, sigmoid ----
    {
      float p = 0.f;
#pragma unroll
      for (int d = 0; d < 64; ++d) p = fmaf(h[d], w_out[d], p);
      LGKM0;
      rowW[0] = p;
      LGKM0;
      float ps = 0.f;
#pragma unroll
      for (int tk = 0; tk < 12; ++tk) ps += Tw[(tk * 5 + slc) * 36];
      if (valid && t == 0) {
        float logit = ps * (1.f / 12.f) + b_out[0];
        int hf = ((sp >> 4) << 4) | (s_raw >> 4);
        int wf = ((sp & 15) << 4) | (s_raw & 15);
        out[hf * 256 + wf] = 1.f / (1.f + expf(-logit));
      }
    }
  } // pass loop
}

extern "C" void kernel_launch(void* const* d_in, const int* in_sizes, int n_in,
                              void* d_out, int out_size, void* d_ws, size_t ws_size,
                              hipStream_t stream) {
  (void)in_sizes; (void)n_in; (void)d_ws; (void)ws_size; (void)out_size;
  prithvi_fused<<<256, 512, 0, stream>>>(
    (const float*)d_in[0],  (const float*)d_in[1],  (const float*)d_in[2],
    (const float*)d_in[3],  (const float*)d_in[4],  (const float*)d_in[5],
    (const float*)d_in[6],  (const float*)d_in[7],  (const float*)d_in[8],
    (const float*)d_in[9],  (const float*)d_in[10], (const float*)d_in[11],
    (const float*)d_in[12], (const float*)d_in[13], (const float*)d_in[14],
    (const float*)d_in[15], (const float*)d_in[16], (const float*)d_in[17],
    (const float*)d_in[18], (const float*)d_in[19], (const float*)d_in[20],
    (float*)d_out);
}